// Round 2
// baseline (5042.337 us; speedup 1.0000x reference)
//
#include <hip/hip_runtime.h>
#include <hip/hip_bf16.h>
#include <stdint.h>

// ---------------- problem constants ----------------
constexpr int Hh  = 768;     // hidden
constexpr int Ss  = 256;     // seq len
constexpr int Bb  = 32;      // batch
constexpr int G4  = 4 * Hh;  // 3072 gate cols
constexpr int MR  = Bb * Ss; // 8192 rows of the big GEMMs
constexpr int NWG = 48;      // LSTM workgroups (all co-resident)
constexpr int UPW = Hh / NWG; // hidden units per WG = 16
constexpr int LC  = 4 * UPW;  // local gate cols per WG = 64
constexpr int WPAD = Hh + 8;  // padded LDS row for weights

typedef short bf16x8 __attribute__((ext_vector_type(8)));
typedef unsigned short u16x8 __attribute__((ext_vector_type(8)));
typedef float f32x4  __attribute__((ext_vector_type(4)));
typedef float f32x2  __attribute__((ext_vector_type(2)));

__device__ __forceinline__ unsigned short f2bf(float f) {
  union { float f; uint32_t u; } v; v.f = f;
  uint32_t u = v.u;
  return (unsigned short)((u + 0x7FFFu + ((u >> 16) & 1u)) >> 16); // RNE
}
__device__ __forceinline__ float bf2f(unsigned short h) {
  union { uint32_t u; float f; } v; v.u = ((uint32_t)h) << 16; return v.f;
}

// ---------------- embedding gather + bf16 cast ----------------
__global__ __launch_bounds__(256) void k_embed(const int* __restrict__ ids,
                                               const float* __restrict__ table,
                                               unsigned short* __restrict__ x_bf) {
  int row = blockIdx.x;                 // b*S+s
  int id  = ids[row];
  const float* src = table + (size_t)id * Hh;
  unsigned short* dst = x_bf + (size_t)row * Hh;
  for (int j = threadIdx.x; j < Hh; j += 256) dst[j] = f2bf(src[j]);
}

// ---------------- fp32 -> bf16 cast (4 elems/thread) ----------------
__global__ __launch_bounds__(256) void k_cast(const float* __restrict__ src,
                                              unsigned short* __restrict__ dst, int n4) {
  int i = blockIdx.x * 256 + threadIdx.x;
  if (i < n4) {
    float4 v = ((const float4*)src)[i];
    uint2 o;
    o.x = (uint32_t)f2bf(v.x) | ((uint32_t)f2bf(v.y) << 16);
    o.y = (uint32_t)f2bf(v.z) | ((uint32_t)f2bf(v.w) << 16);
    ((uint2*)dst)[i] = o;
  }
}

// ---------------- MFMA bf16 TN GEMM (unchanged from round 1) ----------------
__global__ __launch_bounds__(256) void k_gemm_bt(const unsigned short* __restrict__ A,
                                                 const unsigned short* __restrict__ Bw,
                                                 unsigned short* __restrict__ C,
                                                 const float* __restrict__ bias1,
                                                 const float* __restrict__ bias2,
                                                 int M, int N, int K) {
  constexpr int BM = 128, BN = 128, BK = 64;
  __shared__ unsigned short Asm[BM * BK];
  __shared__ unsigned short Bsm[BN * BK];
  const int tid = threadIdx.x, lane = tid & 63, wave = tid >> 6;
  const int m0 = blockIdx.x * BM, n0 = blockIdx.y * BN;
  const int wm = (wave & 1) * 64, wn = (wave >> 1) * 64;

  f32x4 acc[4][4];
  #pragma unroll
  for (int a = 0; a < 4; ++a)
    #pragma unroll
    for (int b = 0; b < 4; ++b) acc[a][b] = (f32x4){0.f, 0.f, 0.f, 0.f};

  const int nk = K / BK;
  bf16x8 ar[4], br[4];
  #pragma unroll
  for (int r = 0; r < 4; ++r) {
    int fb = r * 4096 + tid * 16;
    int row = fb >> 7;
    int kb  = (fb >> 4) & 7;
    ar[r] = *(const bf16x8*)(A  + (size_t)(m0 + row) * K + kb * 8);
    br[r] = *(const bf16x8*)(Bw + (size_t)(n0 + row) * K + kb * 8);
  }
  for (int it = 0; it < nk; ++it) {
    __syncthreads();
    #pragma unroll
    for (int r = 0; r < 4; ++r) {
      int fb = r * 4096 + tid * 16;
      int row = fb >> 7;
      int kb  = (fb >> 4) & 7;
      int sb  = kb ^ (row & 7);
      *(bf16x8*)((char*)Asm + row * 128 + sb * 16) = ar[r];
      *(bf16x8*)((char*)Bsm + row * 128 + sb * 16) = br[r];
    }
    __syncthreads();
    if (it + 1 < nk) {
      int k0 = (it + 1) * BK;
      #pragma unroll
      for (int r = 0; r < 4; ++r) {
        int fb = r * 4096 + tid * 16;
        int row = fb >> 7;
        int kb  = (fb >> 4) & 7;
        ar[r] = *(const bf16x8*)(A  + (size_t)(m0 + row) * K + k0 + kb * 8);
        br[r] = *(const bf16x8*)(Bw + (size_t)(n0 + row) * K + k0 + kb * 8);
      }
    }
    #pragma unroll
    for (int kk = 0; kk < 2; ++kk) {
      bf16x8 af[4], bfr[4];
      #pragma unroll
      for (int mi = 0; mi < 4; ++mi) {
        int row = wm + mi * 16 + (lane & 15);
        int kb  = kk * 4 + (lane >> 4);
        int sb  = kb ^ (row & 7);
        af[mi] = *(const bf16x8*)((const char*)Asm + row * 128 + sb * 16);
      }
      #pragma unroll
      for (int ni = 0; ni < 4; ++ni) {
        int row = wn + ni * 16 + (lane & 15);
        int kb  = kk * 4 + (lane >> 4);
        int sb  = kb ^ (row & 7);
        bfr[ni] = *(const bf16x8*)((const char*)Bsm + row * 128 + sb * 16);
      }
      #pragma unroll
      for (int mi = 0; mi < 4; ++mi)
        #pragma unroll
        for (int ni = 0; ni < 4; ++ni)
          acc[mi][ni] = __builtin_amdgcn_mfma_f32_16x16x32_bf16(af[mi], bfr[ni], acc[mi][ni], 0, 0, 0);
    }
  }
  #pragma unroll
  for (int mi = 0; mi < 4; ++mi)
    #pragma unroll
    for (int ni = 0; ni < 4; ++ni)
      #pragma unroll
      for (int r = 0; r < 4; ++r) {
        int row = wm + mi * 16 + (lane >> 4) * 4 + r;
        int col = wn + ni * 16 + (lane & 15);
        float v = acc[mi][ni][r] + bias1[n0 + col] + bias2[n0 + col];
        C[(size_t)(m0 + row) * N + n0 + col] = f2bf(v);
      }
}

// ---------------- LSTM recurrence: 48 persistent WGs, per-WG flag sync ----------
// g_bf: (B,S,4H) bf16 = x@W_ih^T + b_ih + b_hh.  w_bf: (4H,H) bf16.
// out_bf: (B,S,H) bf16 h-sequence. flags[wg] = #steps completed by wg (zeroed).
__global__ __launch_bounds__(256, 1) void k_lstm(const unsigned short* __restrict__ g_bf,
                                                 const unsigned short* __restrict__ w_bf,
                                                 unsigned short* __restrict__ out_bf,
                                                 unsigned int* __restrict__ flags) {
  __shared__ unsigned short Bsm[LC * WPAD];   // 64 x 776 bf16 = 97 KB
  __shared__ float gsm[Bb][65];               // activated gates, padded

  const int tid = threadIdx.x, lane = tid & 63, w = tid >> 6;
  const int wg = blockIdx.x, u0 = wg * UPW;

  // ---- stage persistent weight slice into LDS (once) ----
  {
    const int cpr = Hh / 8;                   // 96 16B-chunks per row
    for (int c = tid; c < LC * cpr; c += 256) {
      int row = c / cpr, kc = c - row * cpr;
      int gi = row >> 4, u = row & 15;
      *(bf16x8*)&Bsm[row * WPAD + kc * 8] =
        *(const bf16x8*)(w_bf + (size_t)(gi * Hh + u0 + u) * Hh + kc * 8);
    }
  }
  __syncthreads();

  const int mtile = w & 1, nt2 = w >> 1;      // 16 b-rows x 32 cols per wave
  const int kq = lane >> 4, l15 = lane & 15;
  const int brow = mtile * 16 + l15;

  // gin element offsets for [ct*4+r]
  int goff[8];
  #pragma unroll
  for (int ct = 0; ct < 2; ++ct)
    #pragma unroll
    for (int r = 0; r < 4; ++r) {
      int b = mtile * 16 + kq * 4 + r;
      int gcol = (nt2 * 2 + ct) * Hh + u0 + l15;
      goff[ct * 4 + r] = b * (Ss * G4) + gcol;
    }

  u16x8 gcur, gnext;
  #pragma unroll
  for (int j = 0; j < 8; ++j) gcur[j] = g_bf[(size_t)goff[j]];

  float cc[8];
  #pragma unroll
  for (int u = 0; u < 8; ++u) cc[u] = 0.f;

  const int flidx = (lane < NWG) ? lane : 0;

  for (int t = 0; t < Ss; ++t) {
    // prefetch next step's input-gate values (independent of h)
    if (t + 1 < Ss) {
      #pragma unroll
      for (int j = 0; j < 8; ++j) gnext[j] = g_bf[(size_t)goff[j] + (size_t)(t + 1) * G4];
    }

    f32x4 accs[2];
    accs[0] = (f32x4){0.f, 0.f, 0.f, 0.f};
    accs[1] = (f32x4){0.f, 0.f, 0.f, 0.f};

    if (t > 0) {
      // wait until every WG has published step t-1 (monotone per-WG flags)
      for (;;) {
        unsigned f = __hip_atomic_load(flags + flidx, __ATOMIC_RELAXED, __HIP_MEMORY_SCOPE_AGENT);
        if (__all((int)f >= t)) break;
        __builtin_amdgcn_s_sleep(1);
      }
      __builtin_amdgcn_fence(__ATOMIC_ACQUIRE, "agent");

      // h_{t-1} @ W_hh^T
      const unsigned short* ap = out_bf + ((size_t)brow * Ss + (t - 1)) * Hh + kq * 8;
      bf16x8 areg[24];
      #pragma unroll
      for (int kk = 0; kk < 24; ++kk) areg[kk] = *(const bf16x8*)(ap + kk * 32);

      f32x4 acc[2][2];
      #pragma unroll
      for (int ct = 0; ct < 2; ++ct) {
        acc[ct][0] = (f32x4){0.f, 0.f, 0.f, 0.f};
        acc[ct][1] = (f32x4){0.f, 0.f, 0.f, 0.f};
      }
      #pragma unroll
      for (int ct = 0; ct < 2; ++ct) {
        const int lc = nt2 * 32 + ct * 16 + l15;
        #pragma unroll
        for (int kk = 0; kk < 24; ++kk) {
          bf16x8 bfr = *(const bf16x8*)&Bsm[lc * WPAD + kk * 32 + kq * 8];
          acc[ct][kk & 1] = __builtin_amdgcn_mfma_f32_16x16x32_bf16(areg[kk], bfr, acc[ct][kk & 1], 0, 0, 0);
        }
      }
      accs[0] = acc[0][0] + acc[0][1];
      accs[1] = acc[1][0] + acc[1][1];
    }

    // activations -> gsm  (gate index uniform per (wave, ct): no divergence)
    #pragma unroll
    for (int ct = 0; ct < 2; ++ct) {
      const int gi = nt2 * 2 + ct;
      #pragma unroll
      for (int r = 0; r < 4; ++r) {
        float v = accs[ct][r] + bf2f(gcur[ct * 4 + r]);
        float a;
        if (gi == 2) { float e = __expf(-2.f * v); a = (1.f - e) / (1.f + e); }
        else         { a = 1.f / (1.f + __expf(-v)); }
        gsm[mtile * 16 + kq * 4 + r][nt2 * 32 + ct * 16 + l15] = a;
      }
    }
    gcur = gnext;
    __syncthreads();   // gsm complete

    if (w == 0) {
      // pointwise c/h for 32 b x 16 u, c lives in wave-0 registers
      const int b = lane & 31, ub = (lane >> 5) * 8;
      float hv[8];
      #pragma unroll
      for (int u = 0; u < 8; ++u) {
        float iv = gsm[b][ub + u];
        float fv = gsm[b][16 + ub + u];
        float gv = gsm[b][32 + ub + u];
        float ov = gsm[b][48 + ub + u];
        float c = fv * cc[u] + iv * gv;
        cc[u] = c;
        float e = __expf(-2.f * c);
        hv[u] = ov * (1.f - e) / (1.f + e);
      }
      uint32_t* hp = (uint32_t*)(out_bf + ((size_t)b * Ss + t) * Hh + u0 + ub);
      #pragma unroll
      for (int j = 0; j < 4; ++j) {
        uint32_t pk = (uint32_t)f2bf(hv[2 * j]) | ((uint32_t)f2bf(hv[2 * j + 1]) << 16);
        __hip_atomic_store(hp + j, pk, __ATOMIC_RELAXED, __HIP_MEMORY_SCOPE_AGENT);
      }
      asm volatile("s_waitcnt vmcnt(0)" ::: "memory");   // h stores acked at LLC
      if (lane == 0)
        __hip_atomic_store(flags + wg, (unsigned)(t + 1), __ATOMIC_RELAXED, __HIP_MEMORY_SCOPE_AGENT);
    }
    // other waves run ahead to the next poll; gsm reuse is gated by our own flag
  }
}

// ---------------- pool partial (unchanged) ----------------
__global__ __launch_bounds__(256) void k_pool_partial(const unsigned short* __restrict__ out2,
                                                      const float* __restrict__ pw,
                                                      float* __restrict__ partial) {
  __shared__ unsigned short osm[Hh * Bb];
  const int tid = threadIdx.x;
  const int s = blockIdx.x;
  for (int b = 0; b < Bb; ++b) {
    const unsigned short* src = out2 + ((size_t)b * Ss + s) * Hh;
    for (int k = tid; k < Hh; k += 256) osm[k * Bb + b] = src[k];
  }
  __syncthreads();
  f32x2 acc[16][3];
  #pragma unroll
  for (int bp = 0; bp < 16; ++bp)
    #pragma unroll
    for (int j = 0; j < 3; ++j) acc[bp][j] = (f32x2){0.f, 0.f};
  const float* pbase = pw + (size_t)s * Hh * Hh;
  #pragma unroll 2
  for (int k = 0; k < Hh; ++k) {
    float w0 = pbase[(size_t)k * Hh + tid];
    float w1 = pbase[(size_t)k * Hh + 256 + tid];
    float w2 = pbase[(size_t)k * Hh + 512 + tid];
    const uint32_t* orow = (const uint32_t*)&osm[k * Bb];
    #pragma unroll
    for (int bp = 0; bp < 16; ++bp) {
      uint32_t pv = orow[bp];
      f32x2 ov;
      ov.x = __uint_as_float(pv << 16);
      ov.y = __uint_as_float(pv & 0xffff0000u);
      acc[bp][0] += ov * w0;
      acc[bp][1] += ov * w1;
      acc[bp][2] += ov * w2;
    }
  }
  float* pout = partial + (size_t)s * (Bb * Hh);
  #pragma unroll
  for (int bp = 0; bp < 16; ++bp)
    #pragma unroll
    for (int j = 0; j < 3; ++j) {
      pout[(size_t)(bp * 2 + 0) * Hh + j * 256 + tid] = acc[bp][j].x;
      pout[(size_t)(bp * 2 + 1) * Hh + j * 256 + tid] = acc[bp][j].y;
    }
}

__global__ __launch_bounds__(256) void k_pool_reduce(const float* __restrict__ partial,
                                                     const float* __restrict__ pool_b,
                                                     float* __restrict__ seq_out) {
  int i = blockIdx.x * 256 + threadIdx.x;
  float acc = pool_b[i % Hh];
  #pragma unroll 8
  for (int t = 0; t < Ss; ++t) acc += partial[(size_t)t * (Bb * Hh) + i];
  seq_out[i] = acc;
}

// ---------------- entity masked max + logits (unchanged) ----------------
__global__ __launch_bounds__(256) void k_entity_logits(const unsigned short* __restrict__ out2,
                                                       const float* __restrict__ seq_out,
                                                       const int* __restrict__ entity_ids,
                                                       const float* __restrict__ lin_w,
                                                       const float* __restrict__ lin_b,
                                                       float* __restrict__ logits_ws,
                                                       float* __restrict__ dlogits) {
  const int b = blockIdx.x, tid = threadIdx.x;
  float m0 = -1e30f, m1 = -1e30f, m2 = -1e30f;
  for (int s = 0; s < Ss; ++s) {
    bool e = entity_ids[b * Ss + s] == 1;
    const unsigned short* row = out2 + ((size_t)b * Ss + s) * Hh;
    float v0 = bf2f(row[tid]);
    float v1 = bf2f(row[256 + tid]);
    float v2 = bf2f(row[512 + tid]);
    v0 = e ? v0 : 0.f; v1 = e ? v1 : 0.f; v2 = e ? v2 : 0.f;
    m0 = fmaxf(m0, v0); m1 = fmaxf(m1, v1); m2 = fmaxf(m2, v2);
  }
  __shared__ float red[512];
  float p0 = 0.f, p1 = 0.f;
  float mm[3] = {m0, m1, m2};
  #pragma unroll
  for (int j = 0; j < 3; ++j) {
    int n = j * 256 + tid;
    float bo = fmaxf(mm[j], seq_out[b * Hh + n]);
    p0 += bo * lin_w[n * 2 + 0];
    p1 += bo * lin_w[n * 2 + 1];
  }
  red[tid] = p0; red[256 + tid] = p1;
  __syncthreads();
  for (int off = 128; off > 0; off >>= 1) {
    if (tid < off) { red[tid] += red[tid + off]; red[256 + tid] += red[256 + tid + off]; }
    __syncthreads();
  }
  if (tid == 0) {
    float l0 = red[0] + lin_b[0], l1 = red[256] + lin_b[1];
    logits_ws[b * 2] = l0; logits_ws[b * 2 + 1] = l1;
    dlogits[b * 2] = l0;  dlogits[b * 2 + 1] = l1;
  }
}

// ---------------- BCEWithLogits mean loss ----------------
__global__ void k_loss(const float* __restrict__ logits, const int* __restrict__ lab,
                       float* __restrict__ dout) {
  __shared__ float red[64];
  int i = threadIdx.x;
  float l = logits[i];
  float y = (float)lab[i];
  red[i] = fmaxf(l, 0.f) - l * y + log1pf(__expf(-fabsf(l)));
  __syncthreads();
  for (int off = 32; off > 0; off >>= 1) {
    if (i < off) red[i] += red[i + off];
    __syncthreads();
  }
  if (i == 0) dout[0] = red[0] * (1.f / 64.f);
}

// ---------------- launcher ----------------
extern "C" void kernel_launch(void* const* d_in, const int* in_sizes, int n_in,
                              void* d_out, int out_size, void* d_ws, size_t ws_size,
                              hipStream_t stream) {
  const int*   input_ids  = (const int*)d_in[0];
  const int*   seq_label  = (const int*)d_in[3];
  const int*   entity_ids = (const int*)d_in[4];
  const float* embed      = (const float*)d_in[5];
  const float* w_ih0      = (const float*)d_in[6];
  const float* w_hh0      = (const float*)d_in[7];
  const float* b_ih0      = (const float*)d_in[8];
  const float* b_hh0      = (const float*)d_in[9];
  const float* w_ih1      = (const float*)d_in[10];
  const float* w_hh1      = (const float*)d_in[11];
  const float* b_ih1      = (const float*)d_in[12];
  const float* b_hh1      = (const float*)d_in[13];
  const float* pool_w     = (const float*)d_in[14];
  const float* pool_b     = (const float*)d_in[15];
  const float* lin_w      = (const float*)d_in[16];
  const float* lin_b      = (const float*)d_in[17];
  float* out = (float*)d_out;

  const size_t SZ_XO = (size_t)Bb * Ss * Hh * 2;
  const size_t SZ_W  = (size_t)G4 * Hh * 2;
  const size_t SZ_G  = (size_t)Bb * Ss * G4 * 2;
  char* ws = (char*)d_ws;
  size_t off = 0;
  unsigned short* x_bf   = (unsigned short*)(ws + off); off += SZ_XO;   // also out2
  unsigned short* wb_ih0 = (unsigned short*)(ws + off); off += SZ_W;
  unsigned short* wb_hh0 = (unsigned short*)(ws + off); off += SZ_W;
  unsigned short* wb_ih1 = (unsigned short*)(ws + off); off += SZ_W;
  unsigned short* wb_hh1 = (unsigned short*)(ws + off); off += SZ_W;
  unsigned short* g_bf   = (unsigned short*)(ws + off);                 // also partial
  float*          partial= (float*)(ws + off);          off += SZ_G;
  unsigned short* out1_bf= (unsigned short*)(ws + off); off += SZ_XO;
  float*          seq_out= (float*)(ws + off);          off += (size_t)Bb * Hh * 4;
  float*          logits = (float*)(ws + off);          off += 1024;
  unsigned int*   flags  = (unsigned int*)(ws + off);   off += 128 * sizeof(unsigned int);
  unsigned short* out2_bf = x_bf;

  hipMemsetAsync(flags, 0, 128 * sizeof(unsigned int), stream);

  k_embed<<<Bb * Ss, 256, 0, stream>>>(input_ids, embed, x_bf);
  int n4 = (G4 * Hh) / 4;
  int cgrid = (n4 + 255) / 256;
  k_cast<<<cgrid, 256, 0, stream>>>(w_ih0, wb_ih0, n4);
  k_cast<<<cgrid, 256, 0, stream>>>(w_hh0, wb_hh0, n4);
  k_cast<<<cgrid, 256, 0, stream>>>(w_ih1, wb_ih1, n4);
  k_cast<<<cgrid, 256, 0, stream>>>(w_hh1, wb_hh1, n4);

  dim3 ggrid(MR / 128, G4 / 128);
  k_gemm_bt<<<ggrid, 256, 0, stream>>>(x_bf, wb_ih0, g_bf, b_ih0, b_hh0, MR, G4, Hh);
  k_lstm<<<NWG, 256, 0, stream>>>(g_bf, wb_hh0, out1_bf, flags);
  k_gemm_bt<<<ggrid, 256, 0, stream>>>(out1_bf, wb_ih1, g_bf, b_ih1, b_hh1, MR, G4, Hh);
  k_lstm<<<NWG, 256, 0, stream>>>(g_bf, wb_hh1, out2_bf, flags + 64);

  k_pool_partial<<<Ss, 256, 0, stream>>>(out2_bf, pool_w, partial);
  k_pool_reduce<<<(Bb * Hh) / 256, 256, 0, stream>>>(partial, pool_b, seq_out);
  k_entity_logits<<<Bb, 256, 0, stream>>>(out2_bf, seq_out, entity_ids, lin_w, lin_b,
                                          logits, out + 1);
  k_loss<<<1, 64, 0, stream>>>(logits, seq_label, out);
}

// Round 3
// 2746.470 us; speedup vs baseline: 1.8359x; 1.8359x over previous
//
#include <hip/hip_runtime.h>
#include <hip/hip_bf16.h>
#include <stdint.h>

// ---------------- problem constants ----------------
constexpr int Hh  = 768;     // hidden
constexpr int Ss  = 256;     // seq len
constexpr int Bb  = 32;      // batch
constexpr int G4  = 4 * Hh;  // 3072 gate cols
constexpr int MR  = Bb * Ss; // 8192 rows of the big GEMM
constexpr int NWGL = 96;     // LSTM workgroups per layer
constexpr int UPW8 = Hh / NWGL;  // 8 hidden units per WG
constexpr int LCW  = 4 * UPW8;   // 32 gate cols per WG
constexpr int WPAD = Hh + 8;     // padded LDS row for weights

typedef short bf16x8 __attribute__((ext_vector_type(8)));
typedef float f32x4  __attribute__((ext_vector_type(4)));
typedef float f32x2  __attribute__((ext_vector_type(2)));

__device__ __forceinline__ unsigned short f2bf(float f) {
  union { float f; uint32_t u; } v; v.f = f;
  uint32_t u = v.u;
  return (unsigned short)((u + 0x7FFFu + ((u >> 16) & 1u)) >> 16); // RNE
}
__device__ __forceinline__ float bf2f(unsigned short h) {
  union { uint32_t u; float f; } v; v.u = ((uint32_t)h) << 16; return v.f;
}

// ---------------- embedding gather + bf16 cast ----------------
__global__ __launch_bounds__(256) void k_embed(const int* __restrict__ ids,
                                               const float* __restrict__ table,
                                               unsigned short* __restrict__ x_bf) {
  int row = blockIdx.x;                 // b*S+s
  int id  = ids[row];
  const float* src = table + (size_t)id * Hh;
  unsigned short* dst = x_bf + (size_t)row * Hh;
  for (int j = threadIdx.x; j < Hh; j += 256) dst[j] = f2bf(src[j]);
}

// ---------------- fp32 -> bf16 cast (4 elems/thread) ----------------
__global__ __launch_bounds__(256) void k_cast(const float* __restrict__ src,
                                              unsigned short* __restrict__ dst, int n4) {
  int i = blockIdx.x * 256 + threadIdx.x;
  if (i < n4) {
    float4 v = ((const float4*)src)[i];
    uint2 o;
    o.x = (uint32_t)f2bf(v.x) | ((uint32_t)f2bf(v.y) << 16);
    o.y = (uint32_t)f2bf(v.z) | ((uint32_t)f2bf(v.w) << 16);
    ((uint2*)dst)[i] = o;
  }
}

// ---------------- MFMA bf16 TN GEMM. C written in (s, b, N) layout! ----------
// A (M=B*S,K) bf16 row-major (row = b*256+s), Bw (N,K) bf16 row-major.
// C[(s*Bb+b)*N + n] = sum_k A.. + bias1[n] + bias2[n]
__global__ __launch_bounds__(256) void k_gemm_bt(const unsigned short* __restrict__ A,
                                                 const unsigned short* __restrict__ Bw,
                                                 unsigned short* __restrict__ C,
                                                 const float* __restrict__ bias1,
                                                 const float* __restrict__ bias2,
                                                 int M, int N, int K) {
  constexpr int BM = 128, BN = 128, BK = 64;
  __shared__ unsigned short Asm[BM * BK];
  __shared__ unsigned short Bsm[BN * BK];
  const int tid = threadIdx.x, lane = tid & 63, wave = tid >> 6;
  const int m0 = blockIdx.x * BM, n0 = blockIdx.y * BN;
  const int wm = (wave & 1) * 64, wn = (wave >> 1) * 64;

  f32x4 acc[4][4];
  #pragma unroll
  for (int a = 0; a < 4; ++a)
    #pragma unroll
    for (int b = 0; b < 4; ++b) acc[a][b] = (f32x4){0.f, 0.f, 0.f, 0.f};

  const int nk = K / BK;
  bf16x8 ar[4], br[4];
  #pragma unroll
  for (int r = 0; r < 4; ++r) {
    int fb = r * 4096 + tid * 16;
    int row = fb >> 7;
    int kb  = (fb >> 4) & 7;
    ar[r] = *(const bf16x8*)(A  + (size_t)(m0 + row) * K + kb * 8);
    br[r] = *(const bf16x8*)(Bw + (size_t)(n0 + row) * K + kb * 8);
  }
  for (int it = 0; it < nk; ++it) {
    __syncthreads();
    #pragma unroll
    for (int r = 0; r < 4; ++r) {
      int fb = r * 4096 + tid * 16;
      int row = fb >> 7;
      int kb  = (fb >> 4) & 7;
      int sb  = kb ^ (row & 7);
      *(bf16x8*)((char*)Asm + row * 128 + sb * 16) = ar[r];
      *(bf16x8*)((char*)Bsm + row * 128 + sb * 16) = br[r];
    }
    __syncthreads();
    if (it + 1 < nk) {
      int k0 = (it + 1) * BK;
      #pragma unroll
      for (int r = 0; r < 4; ++r) {
        int fb = r * 4096 + tid * 16;
        int row = fb >> 7;
        int kb  = (fb >> 4) & 7;
        ar[r] = *(const bf16x8*)(A  + (size_t)(m0 + row) * K + k0 + kb * 8);
        br[r] = *(const bf16x8*)(Bw + (size_t)(n0 + row) * K + k0 + kb * 8);
      }
    }
    #pragma unroll
    for (int kk = 0; kk < 2; ++kk) {
      bf16x8 af[4], bfr[4];
      #pragma unroll
      for (int mi = 0; mi < 4; ++mi) {
        int row = wm + mi * 16 + (lane & 15);
        int kb  = kk * 4 + (lane >> 4);
        int sb  = kb ^ (row & 7);
        af[mi] = *(const bf16x8*)((const char*)Asm + row * 128 + sb * 16);
      }
      #pragma unroll
      for (int ni = 0; ni < 4; ++ni) {
        int row = wn + ni * 16 + (lane & 15);
        int kb  = kk * 4 + (lane >> 4);
        int sb  = kb ^ (row & 7);
        bfr[ni] = *(const bf16x8*)((const char*)Bsm + row * 128 + sb * 16);
      }
      #pragma unroll
      for (int mi = 0; mi < 4; ++mi)
        #pragma unroll
        for (int ni = 0; ni < 4; ++ni)
          acc[mi][ni] = __builtin_amdgcn_mfma_f32_16x16x32_bf16(af[mi], bfr[ni], acc[mi][ni], 0, 0, 0);
    }
  }
  #pragma unroll
  for (int mi = 0; mi < 4; ++mi)
    #pragma unroll
    for (int ni = 0; ni < 4; ++ni)
      #pragma unroll
      for (int r = 0; r < 4; ++r) {
        int row = m0 + wm + mi * 16 + (lane >> 4) * 4 + r;   // = b*256 + s
        int col = wn + ni * 16 + (lane & 15);
        int bb = row >> 8, ss = row & 255;
        float v = acc[mi][ni][r] + bias1[n0 + col] + bias2[n0 + col];
        C[((size_t)ss * Bb + bb) * N + n0 + col] = f2bf(v);
      }
}

// ---------------- fused 2-layer LSTM, persistent, mailbox-synced -------------
// g_bf: (S,B,4H) bf16 = x@W_ih0^T + biases (layer-1 pre-gates)
// hseq1/hseq2: (S,B,H) bf16 h-sequences (layer outputs)
// sync: [0..95]=flags1, [96..191]=flags2, [256 + i*16]=mailbox_i (i<192)
__global__ __launch_bounds__(256, 1) void k_lstm2(
    const unsigned short* __restrict__ g_bf,
    const unsigned short* __restrict__ w_hh0b,
    const unsigned short* __restrict__ w_ih1b,
    const unsigned short* __restrict__ w_hh1b,
    const float* __restrict__ b_ih1,
    const float* __restrict__ b_hh1,
    unsigned short* __restrict__ hseq1,
    unsigned short* __restrict__ hseq2,
    unsigned int* __restrict__ sync) {
  unsigned int* flags1 = sync;
  unsigned int* flags2 = sync + 96;
  unsigned int* mbox   = sync + 256;
  const int wgid = blockIdx.x;
  const int tid = threadIdx.x;

  if (wgid == 2 * NWGL) {
    // ---- aggregator: one wave polls producer flags, publishes packed epoch ----
    if (tid >= 64) return;
    const int lane = tid;
    int e1 = 0, e2 = 0;
    for (;;) {
      unsigned f1a = __hip_atomic_load(flags1 + lane, __ATOMIC_RELAXED, __HIP_MEMORY_SCOPE_AGENT);
      unsigned f2a = __hip_atomic_load(flags2 + lane, __ATOMIC_RELAXED, __HIP_MEMORY_SCOPE_AGENT);
      unsigned f1b = 0xffffu, f2b = 0xffffu;
      if (lane < 32) {
        f1b = __hip_atomic_load(flags1 + 64 + lane, __ATOMIC_RELAXED, __HIP_MEMORY_SCOPE_AGENT);
        f2b = __hip_atomic_load(flags2 + 64 + lane, __ATOMIC_RELAXED, __HIP_MEMORY_SCOPE_AGENT);
      }
      bool adv1 = (e1 < Ss) && __all(f1a > (unsigned)e1) && __all(f1b > (unsigned)e1);
      bool adv2 = (e2 < Ss) && __all(f2a > (unsigned)e2) && __all(f2b > (unsigned)e2);
      if (adv1) ++e1;
      if (adv2) ++e2;
      if (adv1 || adv2) {
        unsigned pk = ((unsigned)e1 << 16) | (unsigned)e2;
        __hip_atomic_store(mbox + (size_t)lane * 16, pk, __ATOMIC_RELAXED, __HIP_MEMORY_SCOPE_AGENT);
        __hip_atomic_store(mbox + (size_t)(lane + 64) * 16, pk, __ATOMIC_RELAXED, __HIP_MEMORY_SCOPE_AGENT);
        __hip_atomic_store(mbox + (size_t)(lane + 128) * 16, pk, __ATOMIC_RELAXED, __HIP_MEMORY_SCOPE_AGENT);
        if (e1 >= Ss && e2 >= Ss) break;
      } else {
        __builtin_amdgcn_s_sleep(1);
      }
    }
    return;
  }

  // ---- compute workgroups ----
  __shared__ unsigned short Whh[LCW * WPAD];   // 48.5 KB
  __shared__ unsigned short Wih[LCW * WPAD];   // 48.5 KB (layer-2 only)
  __shared__ float gsm[Bb][36];                // activated gates, pad 36 (2-way max)
  __shared__ unsigned short hsm[Bb][UPW8];

  const int layer = wgid >= NWGL;
  const int wg = layer ? wgid - NWGL : wgid;
  const int u0 = wg * UPW8;

  {
    const int cpr = Hh / 8;   // 96 16B chunks per row
    const unsigned short* src = layer ? w_hh1b : w_hh0b;
    for (int cch = tid; cch < LCW * cpr; cch += 256) {
      int row = cch / cpr, kc = cch - row * cpr;
      int gi = row >> 3, u = row & 7;
      *(bf16x8*)&Whh[row * WPAD + kc * 8] =
          *(const bf16x8*)(src + (size_t)(gi * Hh + u0 + u) * Hh + kc * 8);
    }
    if (layer) {
      for (int cch = tid; cch < LCW * cpr; cch += 256) {
        int row = cch / cpr, kc = cch - row * cpr;
        int gi = row >> 3, u = row & 7;
        *(bf16x8*)&Wih[row * WPAD + kc * 8] =
            *(const bf16x8*)(w_ih1b + (size_t)(gi * Hh + u0 + u) * Hh + kc * 8);
      }
    }
  }
  __syncthreads();

  const int lane = tid & 63, w = tid >> 6;
  const int mtile = w & 1, nt2 = w >> 1;
  const int l15 = lane & 15, kq = lane >> 4;
  const int brow = mtile * 16 + l15;
  const int c = nt2 * 16 + l15;                   // local gate col 0..31
  const int gi = c >> 3;
  const int gcol = gi * Hh + u0 + (c & 7);        // global gate col
  const float kmul = (gi == 2) ? 2.f : 1.f;       // tanh via 2*sigm(2v)-1
  const float amul = (gi == 2) ? 2.f : 1.f;
  const float aadd = (gi == 2) ? -1.f : 0.f;
  float bl = 0.f;
  if (layer) bl = b_ih1[gcol] + b_hh1[gcol];

  unsigned short gc[4];
  if (!layer) {
    #pragma unroll
    for (int r = 0; r < 4; ++r) {
      int b = mtile * 16 + kq * 4 + r;
      gc[r] = g_bf[(size_t)b * G4 + gcol];        // t = 0
    }
  }
  float cc = 0.f;                                 // c-state for (b=tid>>3, u=tid&7)
  unsigned short* hout = layer ? hseq2 : hseq1;
  unsigned int* myflags = layer ? flags2 : flags1;

  for (int t = 0; t < Ss; ++t) {
    if (layer || t > 0) {
      const unsigned need1 = layer ? (unsigned)(t + 1) : (unsigned)t;
      const unsigned need2 = layer ? (unsigned)t : 0u;
      for (;;) {
        unsigned pk = __hip_atomic_load(mbox + (size_t)wgid * 16, __ATOMIC_RELAXED, __HIP_MEMORY_SCOPE_AGENT);
        if ((pk >> 16) >= need1 && (pk & 0xffffu) >= need2) break;
      }
      asm volatile("" ::: "memory");
    }

    f32x4 a0 = {0.f, 0.f, 0.f, 0.f}, a1 = {0.f, 0.f, 0.f, 0.f};
    if (layer) {
      // gates += h1[t] @ W_ih1^T
      const unsigned short* ap = hseq1 + ((size_t)t * Bb + brow) * Hh + kq * 8;
      bf16x8 areg[24];
      #pragma unroll
      for (int kk = 0; kk < 24; ++kk) areg[kk] = *(const bf16x8*)(ap + kk * 32);
      #pragma unroll
      for (int kk = 0; kk < 24; ++kk) {
        bf16x8 bfr = *(const bf16x8*)&Wih[c * WPAD + kk * 32 + kq * 8];
        if (kk & 1) a1 = __builtin_amdgcn_mfma_f32_16x16x32_bf16(areg[kk], bfr, a1, 0, 0, 0);
        else        a0 = __builtin_amdgcn_mfma_f32_16x16x32_bf16(areg[kk], bfr, a0, 0, 0, 0);
      }
    }
    if (t > 0) {
      // gates += h_own[t-1] @ W_hh^T
      const unsigned short* ap = hout + ((size_t)(t - 1) * Bb + brow) * Hh + kq * 8;
      bf16x8 areg[24];
      #pragma unroll
      for (int kk = 0; kk < 24; ++kk) areg[kk] = *(const bf16x8*)(ap + kk * 32);
      #pragma unroll
      for (int kk = 0; kk < 24; ++kk) {
        bf16x8 bfr = *(const bf16x8*)&Whh[c * WPAD + kk * 32 + kq * 8];
        if (kk & 1) a1 = __builtin_amdgcn_mfma_f32_16x16x32_bf16(areg[kk], bfr, a1, 0, 0, 0);
        else        a0 = __builtin_amdgcn_mfma_f32_16x16x32_bf16(areg[kk], bfr, a0, 0, 0, 0);
      }
    }

    // activations -> gsm
    #pragma unroll
    for (int r = 0; r < 4; ++r) {
      float v = a0[r] + a1[r] + (layer ? bl : bf2f(gc[r]));
      float s = 1.f / (1.f + __expf(-kmul * v));
      gsm[mtile * 16 + kq * 4 + r][c] = amul * s + aadd;
    }
    __syncthreads();

    // pointwise c/h: 256 threads = 32 b x 8 u, c in registers
    {
      const int b = tid >> 3, u = tid & 7;
      float iv = gsm[b][u], fv = gsm[b][8 + u], gv = gsm[b][16 + u], ov = gsm[b][24 + u];
      float cnew = fv * cc + iv * gv;
      cc = cnew;
      float e = __expf(-2.f * cnew);
      hsm[b][u] = f2bf(ov * (1.f - e) / (1.f + e));
    }
    __syncthreads();

    if (w == 0) {
      // publish h slice: (S,B,H) layout, 8B per lane, then flag
      const int b = lane >> 1, half = lane & 1;
      uint2 hv = *(const uint2*)&hsm[b][half * 4];
      uint32_t* hp = (uint32_t*)(hout + ((size_t)t * Bb + b) * Hh + u0 + half * 4);
      __hip_atomic_store(hp + 0, hv.x, __ATOMIC_RELAXED, __HIP_MEMORY_SCOPE_AGENT);
      __hip_atomic_store(hp + 1, hv.y, __ATOMIC_RELAXED, __HIP_MEMORY_SCOPE_AGENT);
      asm volatile("s_waitcnt vmcnt(0)" ::: "memory");   // h visible at LLC
      if (lane == 0)
        __hip_atomic_store(myflags + wg, (unsigned)(t + 1), __ATOMIC_RELAXED, __HIP_MEMORY_SCOPE_AGENT);
    }
    // prefetch next-step pre-gates (after flag publish: doesn't delay it)
    if (!layer && t + 1 < Ss) {
      #pragma unroll
      for (int r = 0; r < 4; ++r) {
        int b = mtile * 16 + kq * 4 + r;
        gc[r] = g_bf[((size_t)(t + 1) * Bb + b) * G4 + gcol];
      }
    }
  }
}

// ---------------- pool partial: partial[s][b][n] over hseq2 (S,B,H) ----------
__global__ __launch_bounds__(256) void k_pool_partial(const unsigned short* __restrict__ hseq2,
                                                      const float* __restrict__ pw,
                                                      float* __restrict__ partial) {
  __shared__ unsigned short osm[Hh * Bb];  // [k][b] bf16
  const int tid = threadIdx.x;
  const int s = blockIdx.x;
  for (int b = 0; b < Bb; ++b) {
    const unsigned short* src = hseq2 + ((size_t)s * Bb + b) * Hh;
    for (int k = tid; k < Hh; k += 256) osm[k * Bb + b] = src[k];
  }
  __syncthreads();
  f32x2 acc[16][3];
  #pragma unroll
  for (int bp = 0; bp < 16; ++bp)
    #pragma unroll
    for (int j = 0; j < 3; ++j) acc[bp][j] = (f32x2){0.f, 0.f};
  const float* pbase = pw + (size_t)s * Hh * Hh;
  #pragma unroll 2
  for (int k = 0; k < Hh; ++k) {
    float w0 = pbase[(size_t)k * Hh + tid];
    float w1 = pbase[(size_t)k * Hh + 256 + tid];
    float w2 = pbase[(size_t)k * Hh + 512 + tid];
    const uint32_t* orow = (const uint32_t*)&osm[k * Bb];
    #pragma unroll
    for (int bp = 0; bp < 16; ++bp) {
      uint32_t pv = orow[bp];
      f32x2 ov;
      ov.x = __uint_as_float(pv << 16);
      ov.y = __uint_as_float(pv & 0xffff0000u);
      acc[bp][0] += ov * w0;
      acc[bp][1] += ov * w1;
      acc[bp][2] += ov * w2;
    }
  }
  float* pout = partial + (size_t)s * (Bb * Hh);
  #pragma unroll
  for (int bp = 0; bp < 16; ++bp)
    #pragma unroll
    for (int j = 0; j < 3; ++j) {
      pout[(size_t)(bp * 2 + 0) * Hh + j * 256 + tid] = acc[bp][j].x;
      pout[(size_t)(bp * 2 + 1) * Hh + j * 256 + tid] = acc[bp][j].y;
    }
}

__global__ __launch_bounds__(256) void k_pool_reduce(const float* __restrict__ partial,
                                                     const float* __restrict__ pool_b,
                                                     float* __restrict__ seq_out) {
  int i = blockIdx.x * 256 + threadIdx.x;
  float acc = pool_b[i % Hh];
  #pragma unroll 8
  for (int t = 0; t < Ss; ++t) acc += partial[(size_t)t * (Bb * Hh) + i];
  seq_out[i] = acc;
}

// ---------------- entity masked max + logits (hseq2 in (S,B,H)) --------------
__global__ __launch_bounds__(256) void k_entity_logits(const unsigned short* __restrict__ hseq2,
                                                       const float* __restrict__ seq_out,
                                                       const int* __restrict__ entity_ids,
                                                       const float* __restrict__ lin_w,
                                                       const float* __restrict__ lin_b,
                                                       float* __restrict__ logits_ws,
                                                       float* __restrict__ dlogits) {
  const int b = blockIdx.x, tid = threadIdx.x;
  float m0 = -1e30f, m1 = -1e30f, m2 = -1e30f;
  for (int s = 0; s < Ss; ++s) {
    bool e = entity_ids[b * Ss + s] == 1;
    const unsigned short* row = hseq2 + ((size_t)s * Bb + b) * Hh;
    float v0 = bf2f(row[tid]);
    float v1 = bf2f(row[256 + tid]);
    float v2 = bf2f(row[512 + tid]);
    v0 = e ? v0 : 0.f; v1 = e ? v1 : 0.f; v2 = e ? v2 : 0.f;
    m0 = fmaxf(m0, v0); m1 = fmaxf(m1, v1); m2 = fmaxf(m2, v2);
  }
  __shared__ float red[512];
  float p0 = 0.f, p1 = 0.f;
  float mm[3] = {m0, m1, m2};
  #pragma unroll
  for (int j = 0; j < 3; ++j) {
    int n = j * 256 + tid;
    float bo = fmaxf(mm[j], seq_out[b * Hh + n]);
    p0 += bo * lin_w[n * 2 + 0];
    p1 += bo * lin_w[n * 2 + 1];
  }
  red[tid] = p0; red[256 + tid] = p1;
  __syncthreads();
  for (int off = 128; off > 0; off >>= 1) {
    if (tid < off) { red[tid] += red[tid + off]; red[256 + tid] += red[256 + tid + off]; }
    __syncthreads();
  }
  if (tid == 0) {
    float l0 = red[0] + lin_b[0], l1 = red[256] + lin_b[1];
    logits_ws[b * 2] = l0; logits_ws[b * 2 + 1] = l1;
    dlogits[b * 2] = l0;  dlogits[b * 2 + 1] = l1;
  }
}

// ---------------- BCEWithLogits mean loss ----------------
__global__ void k_loss(const float* __restrict__ logits, const int* __restrict__ lab,
                       float* __restrict__ dout) {
  __shared__ float red[64];
  int i = threadIdx.x;
  float l = logits[i];
  float y = (float)lab[i];
  red[i] = fmaxf(l, 0.f) - l * y + log1pf(__expf(-fabsf(l)));
  __syncthreads();
  for (int off = 32; off > 0; off >>= 1) {
    if (i < off) red[i] += red[i + off];
    __syncthreads();
  }
  if (i == 0) dout[0] = red[0] * (1.f / 64.f);
}

// ---------------- launcher ----------------
extern "C" void kernel_launch(void* const* d_in, const int* in_sizes, int n_in,
                              void* d_out, int out_size, void* d_ws, size_t ws_size,
                              hipStream_t stream) {
  const int*   input_ids  = (const int*)d_in[0];
  const int*   seq_label  = (const int*)d_in[3];
  const int*   entity_ids = (const int*)d_in[4];
  const float* embed      = (const float*)d_in[5];
  const float* w_ih0      = (const float*)d_in[6];
  const float* w_hh0      = (const float*)d_in[7];
  const float* b_ih0      = (const float*)d_in[8];
  const float* b_hh0      = (const float*)d_in[9];
  const float* w_ih1      = (const float*)d_in[10];
  const float* w_hh1      = (const float*)d_in[11];
  const float* b_ih1      = (const float*)d_in[12];
  const float* b_hh1      = (const float*)d_in[13];
  const float* pool_w     = (const float*)d_in[14];
  const float* pool_b     = (const float*)d_in[15];
  const float* lin_w      = (const float*)d_in[16];
  const float* lin_b      = (const float*)d_in[17];
  float* out = (float*)d_out;

  const size_t SZ_XO = (size_t)Bb * Ss * Hh * 2;   // 12.58 MB
  const size_t SZ_W  = (size_t)G4 * Hh * 2;        //  4.7 MB
  const size_t SZ_G  = (size_t)Bb * Ss * G4 * 2;   // 50.3 MB
  char* ws = (char*)d_ws;
  size_t off = 0;
  unsigned short* x_bf   = (unsigned short*)(ws + off); off += SZ_XO;
  unsigned short* wb_ih0 = (unsigned short*)(ws + off); off += SZ_W;
  unsigned short* wb_hh0 = (unsigned short*)(ws + off); off += SZ_W;
  unsigned short* wb_ih1 = (unsigned short*)(ws + off); off += SZ_W;
  unsigned short* wb_hh1 = (unsigned short*)(ws + off); off += SZ_W;
  unsigned short* g_bf   = (unsigned short*)(ws + off);                 // aliased: partial
  float*          partial= (float*)(ws + off);          off += SZ_G;
  unsigned short* hseq1  = (unsigned short*)(ws + off); off += SZ_XO;
  unsigned short* hseq2  = (unsigned short*)(ws + off); off += SZ_XO;
  float*          seq_out= (float*)(ws + off);          off += (size_t)Bb * Hh * 4;
  float*          logits = (float*)(ws + off);          off += 1024;
  unsigned int*   syncb  = (unsigned int*)(ws + off);   off += (256 + 192 * 16) * sizeof(unsigned int);

  hipMemsetAsync(syncb, 0, (256 + 192 * 16) * sizeof(unsigned int), stream);

  k_embed<<<Bb * Ss, 256, 0, stream>>>(input_ids, embed, x_bf);
  int n4 = (G4 * Hh) / 4;
  int cgrid = (n4 + 255) / 256;
  k_cast<<<cgrid, 256, 0, stream>>>(w_ih0, wb_ih0, n4);
  k_cast<<<cgrid, 256, 0, stream>>>(w_hh0, wb_hh0, n4);
  k_cast<<<cgrid, 256, 0, stream>>>(w_ih1, wb_ih1, n4);
  k_cast<<<cgrid, 256, 0, stream>>>(w_hh1, wb_hh1, n4);

  dim3 ggrid(MR / 128, G4 / 128);
  k_gemm_bt<<<ggrid, 256, 0, stream>>>(x_bf, wb_ih0, g_bf, b_ih0, b_hh0, MR, G4, Hh);

  k_lstm2<<<2 * NWGL + 1, 256, 0, stream>>>(g_bf, wb_hh0, wb_ih1, wb_hh1,
                                            b_ih1, b_hh1, hseq1, hseq2, syncb);

  k_pool_partial<<<Ss, 256, 0, stream>>>(hseq2, pool_w, partial);
  k_pool_reduce<<<(Bb * Hh) / 256, 256, 0, stream>>>(partial, pool_b, seq_out);
  k_entity_logits<<<Bb, 256, 0, stream>>>(hseq2, seq_out, entity_ids, lin_w, lin_b,
                                          logits, out + 1);
  k_loss<<<1, 64, 0, stream>>>(logits, seq_label, out);
}

// Round 4
// 2723.635 us; speedup vs baseline: 1.8513x; 1.0084x over previous
//
#include <hip/hip_runtime.h>
#include <hip/hip_bf16.h>
#include <stdint.h>

// ---------------- problem constants ----------------
constexpr int Hh  = 768;     // hidden
constexpr int Ss  = 256;     // seq len
constexpr int Bb  = 32;      // batch
constexpr int G4  = 4 * Hh;  // 3072 gate cols
constexpr int MR  = Bb * Ss; // 8192 rows of the big GEMM
constexpr int NWGL = 96;     // LSTM workgroups per layer
constexpr int NPOOL = 63;    // pool workgroups (96+96+63 = 255 <= 256 CUs)
constexpr int UPW8 = Hh / NWGL;  // 8 hidden units per WG
constexpr int LCW  = 4 * UPW8;   // 32 gate cols per WG
constexpr int FLS  = 8;          // flag stride (uints) = 32B

typedef short bf16x8 __attribute__((ext_vector_type(8)));
typedef float f32x4  __attribute__((ext_vector_type(4)));
typedef float f32x2  __attribute__((ext_vector_type(2)));

__device__ __forceinline__ unsigned short f2bf(float f) {
  union { float f; uint32_t u; } v; v.f = f;
  uint32_t u = v.u;
  return (unsigned short)((u + 0x7FFFu + ((u >> 16) & 1u)) >> 16); // RNE
}
__device__ __forceinline__ float bf2f(unsigned short h) {
  union { uint32_t u; float f; } v; v.u = ((uint32_t)h) << 16; return v.f;
}

// ---------------- embedding gather + bf16 cast ----------------
__global__ __launch_bounds__(256) void k_embed(const int* __restrict__ ids,
                                               const float* __restrict__ table,
                                               unsigned short* __restrict__ x_bf) {
  int row = blockIdx.x;                 // b*S+s
  int id  = ids[row];
  const float* src = table + (size_t)id * Hh;
  unsigned short* dst = x_bf + (size_t)row * Hh;
  for (int j = threadIdx.x; j < Hh; j += 256) dst[j] = f2bf(src[j]);
}

// ---------------- fp32 -> bf16 cast (4 elems/thread) ----------------
__global__ __launch_bounds__(256) void k_cast(const float* __restrict__ src,
                                              unsigned short* __restrict__ dst, int n4) {
  int i = blockIdx.x * 256 + threadIdx.x;
  if (i < n4) {
    float4 v = ((const float4*)src)[i];
    uint2 o;
    o.x = (uint32_t)f2bf(v.x) | ((uint32_t)f2bf(v.y) << 16);
    o.y = (uint32_t)f2bf(v.z) | ((uint32_t)f2bf(v.w) << 16);
    ((uint2*)dst)[i] = o;
  }
}

// ---------------- MFMA bf16 TN GEMM. C written in (s, b, N) layout ----------
__global__ __launch_bounds__(256) void k_gemm_bt(const unsigned short* __restrict__ A,
                                                 const unsigned short* __restrict__ Bw,
                                                 unsigned short* __restrict__ C,
                                                 const float* __restrict__ bias1,
                                                 const float* __restrict__ bias2,
                                                 int M, int N, int K) {
  constexpr int BM = 128, BN = 128, BK = 64;
  __shared__ unsigned short Asm[BM * BK];
  __shared__ unsigned short Bsm[BN * BK];
  const int tid = threadIdx.x, lane = tid & 63, wave = tid >> 6;
  const int m0 = blockIdx.x * BM, n0 = blockIdx.y * BN;
  const int wm = (wave & 1) * 64, wn = (wave >> 1) * 64;

  f32x4 acc[4][4];
  #pragma unroll
  for (int a = 0; a < 4; ++a)
    #pragma unroll
    for (int b = 0; b < 4; ++b) acc[a][b] = (f32x4){0.f, 0.f, 0.f, 0.f};

  const int nk = K / BK;
  bf16x8 ar[4], br[4];
  #pragma unroll
  for (int r = 0; r < 4; ++r) {
    int fb = r * 4096 + tid * 16;
    int row = fb >> 7;
    int kb  = (fb >> 4) & 7;
    ar[r] = *(const bf16x8*)(A  + (size_t)(m0 + row) * K + kb * 8);
    br[r] = *(const bf16x8*)(Bw + (size_t)(n0 + row) * K + kb * 8);
  }
  for (int it = 0; it < nk; ++it) {
    __syncthreads();
    #pragma unroll
    for (int r = 0; r < 4; ++r) {
      int fb = r * 4096 + tid * 16;
      int row = fb >> 7;
      int kb  = (fb >> 4) & 7;
      int sb  = kb ^ (row & 7);
      *(bf16x8*)((char*)Asm + row * 128 + sb * 16) = ar[r];
      *(bf16x8*)((char*)Bsm + row * 128 + sb * 16) = br[r];
    }
    __syncthreads();
    if (it + 1 < nk) {
      int k0 = (it + 1) * BK;
      #pragma unroll
      for (int r = 0; r < 4; ++r) {
        int fb = r * 4096 + tid * 16;
        int row = fb >> 7;
        int kb  = (fb >> 4) & 7;
        ar[r] = *(const bf16x8*)(A  + (size_t)(m0 + row) * K + k0 + kb * 8);
        br[r] = *(const bf16x8*)(Bw + (size_t)(n0 + row) * K + k0 + kb * 8);
      }
    }
    #pragma unroll
    for (int kk = 0; kk < 2; ++kk) {
      bf16x8 af[4], bfr[4];
      #pragma unroll
      for (int mi = 0; mi < 4; ++mi) {
        int row = wm + mi * 16 + (lane & 15);
        int kb  = kk * 4 + (lane >> 4);
        int sb  = kb ^ (row & 7);
        af[mi] = *(const bf16x8*)((const char*)Asm + row * 128 + sb * 16);
      }
      #pragma unroll
      for (int ni = 0; ni < 4; ++ni) {
        int row = wn + ni * 16 + (lane & 15);
        int kb  = kk * 4 + (lane >> 4);
        int sb  = kb ^ (row & 7);
        bfr[ni] = *(const bf16x8*)((const char*)Bsm + row * 128 + sb * 16);
      }
      #pragma unroll
      for (int mi = 0; mi < 4; ++mi)
        #pragma unroll
        for (int ni = 0; ni < 4; ++ni)
          acc[mi][ni] = __builtin_amdgcn_mfma_f32_16x16x32_bf16(af[mi], bfr[ni], acc[mi][ni], 0, 0, 0);
    }
  }
  #pragma unroll
  for (int mi = 0; mi < 4; ++mi)
    #pragma unroll
    for (int ni = 0; ni < 4; ++ni)
      #pragma unroll
      for (int r = 0; r < 4; ++r) {
        int row = m0 + wm + mi * 16 + (lane >> 4) * 4 + r;   // = b*256 + s
        int col = wn + ni * 16 + (lane & 15);
        int bb = row >> 8, ss = row & 255;
        float v = acc[mi][ni][r] + bias1[n0 + col] + bias2[n0 + col];
        C[((size_t)ss * Bb + bb) * N + n0 + col] = f2bf(v);
      }
}

// ---------------- fused 2-layer LSTM + pool GEMM, persistent -----------------
// WGs 0..95: layer-1; 96..191: layer-2; 192..254: pool (consume flags2 per-s).
// flags1[i] = sync[i*FLS], flags2[i] = sync[96*FLS + i*FLS]; monotone step counts.
__global__ __launch_bounds__(256) void k_lstm2(
    const unsigned short* __restrict__ g_bf,
    const unsigned short* __restrict__ w_hh0b,
    const unsigned short* __restrict__ w_ih1b,
    const unsigned short* __restrict__ w_hh1b,
    const float* __restrict__ b_ih1,
    const float* __restrict__ b_hh1,
    unsigned short* __restrict__ hseq1,
    unsigned short* __restrict__ hseq2,
    const float* __restrict__ pool_w,
    float* __restrict__ partial,
    unsigned int* __restrict__ sync) {
  __shared__ __align__(16) char smem[2 * LCW * Hh * 2 + Bb * 33 * 4];
  unsigned short* Whh = (unsigned short*)smem;                     // 48 KB, XOR-swizzled
  unsigned short* Wih = (unsigned short*)(smem + LCW * Hh * 2);    // 48 KB (layer-2)
  float (*gsm)[33] = (float(*)[33])(smem + 2 * LCW * Hh * 2);

  const int wgid = blockIdx.x;
  const int tid = threadIdx.x;
  const int lane = tid & 63, w = tid >> 6;
  unsigned int* flags1 = sync;
  unsigned int* flags2 = sync + 96 * FLS;

  if (wgid >= 2 * NWGL) {
    // ================= pool role =================
    const int p = wgid - 2 * NWGL;               // 0..62
    unsigned short* osm = (unsigned short*)smem; // 48 KB [k][b]
    for (int s = p; s < Ss; s += NPOOL) {
      if (w == 0) {
        const unsigned need = (unsigned)(s + 1);
        for (;;) {
          unsigned fa = __hip_atomic_load(flags2 + lane * FLS, __ATOMIC_RELAXED, __HIP_MEMORY_SCOPE_AGENT);
          unsigned fb = __hip_atomic_load(flags2 + (64 + (lane & 31)) * FLS, __ATOMIC_RELAXED, __HIP_MEMORY_SCOPE_AGENT);
          if (__all(fa >= need) && __all(fb >= need)) break;
        }
      }
      __syncthreads();
      asm volatile("" ::: "memory");
      for (int b = 0; b < Bb; ++b) {
        const unsigned short* src = hseq2 + ((size_t)s * Bb + b) * Hh;
        for (int k = tid; k < Hh; k += 256) osm[k * Bb + b] = src[k];
      }
      __syncthreads();
      f32x2 acc[16][3];
      #pragma unroll
      for (int bp = 0; bp < 16; ++bp)
        #pragma unroll
        for (int j = 0; j < 3; ++j) acc[bp][j] = (f32x2){0.f, 0.f};
      const float* pbase = pool_w + (size_t)s * Hh * Hh;
      #pragma unroll 2
      for (int k = 0; k < Hh; ++k) {
        float w0 = pbase[(size_t)k * Hh + tid];
        float w1 = pbase[(size_t)k * Hh + 256 + tid];
        float w2 = pbase[(size_t)k * Hh + 512 + tid];
        const uint32_t* orow = (const uint32_t*)&osm[k * Bb];
        #pragma unroll
        for (int bp = 0; bp < 16; ++bp) {
          uint32_t pv = orow[bp];
          f32x2 ov;
          ov.x = __uint_as_float(pv << 16);
          ov.y = __uint_as_float(pv & 0xffff0000u);
          acc[bp][0] += ov * w0;
          acc[bp][1] += ov * w1;
          acc[bp][2] += ov * w2;
        }
      }
      float* pout = partial + (size_t)s * (Bb * Hh);
      #pragma unroll
      for (int bp = 0; bp < 16; ++bp)
        #pragma unroll
        for (int j = 0; j < 3; ++j) {
          pout[(size_t)(bp * 2 + 0) * Hh + j * 256 + tid] = acc[bp][j].x;
          pout[(size_t)(bp * 2 + 1) * Hh + j * 256 + tid] = acc[bp][j].y;
        }
      __syncthreads();   // osm reuse fence for next s
    }
    return;
  }

  // ================= LSTM role =================
  const int layer = wgid >= NWGL;
  const int wg = layer ? wgid - NWGL : wgid;
  const int u0 = wg * UPW8;

  // stage weight slices into LDS, 16B chunks XOR-swizzled by (row&7)
  {
    const unsigned short* src = layer ? w_hh1b : w_hh0b;
    for (int cch = tid; cch < LCW * 96; cch += 256) {
      int row = cch / 96, kc = cch - row * 96;
      int gi = row >> 3, u = row & 7;
      *(bf16x8*)&Whh[row * Hh + ((kc ^ (row & 7)) * 8)] =
          *(const bf16x8*)(src + (size_t)(gi * Hh + u0 + u) * Hh + kc * 8);
    }
    if (layer) {
      for (int cch = tid; cch < LCW * 96; cch += 256) {
        int row = cch / 96, kc = cch - row * 96;
        int gi = row >> 3, u = row & 7;
        *(bf16x8*)&Wih[row * Hh + ((kc ^ (row & 7)) * 8)] =
            *(const bf16x8*)(w_ih1b + (size_t)(gi * Hh + u0 + u) * Hh + kc * 8);
      }
    }
  }
  __syncthreads();

  const int mtile = w & 1, nt2 = w >> 1;
  const int l15 = lane & 15, kq = lane >> 4;
  const int brow = mtile * 16 + l15;
  const int c = nt2 * 16 + l15;                   // local gate col 0..31
  const int gi = c >> 3;
  const int gcol = gi * Hh + u0 + (c & 7);        // global gate col
  const float kmul = (gi == 2) ? 2.f : 1.f;       // tanh via 2*sigm(2v)-1
  const float amul = (gi == 2) ? 2.f : 1.f;
  const float aadd = (gi == 2) ? -1.f : 0.f;
  float bl = 0.f;
  if (layer) bl = b_ih1[gcol] + b_hh1[gcol];

  unsigned short gc[4];
  if (!layer) {
    #pragma unroll
    for (int r = 0; r < 4; ++r) {
      int b = mtile * 16 + kq * 4 + r;
      gc[r] = g_bf[(size_t)b * G4 + gcol];        // t = 0 pre-gates
    }
  }
  float cc[4] = {0.f, 0.f, 0.f, 0.f};             // wave0: c-state (b=lane&31, u=(lane>>5)*4+j)
  unsigned short* hout = layer ? hseq2 : hseq1;
  unsigned int* myflag = (layer ? flags2 : flags1) + wg * FLS;

  for (int t = 0; t < Ss; ++t) {
    if (w == 0) {
      if (layer) {
        const unsigned need1 = (unsigned)(t + 1), need2 = (unsigned)t;
        for (;;) {
          unsigned f1a = __hip_atomic_load(flags1 + lane * FLS, __ATOMIC_RELAXED, __HIP_MEMORY_SCOPE_AGENT);
          unsigned f1b = __hip_atomic_load(flags1 + (64 + (lane & 31)) * FLS, __ATOMIC_RELAXED, __HIP_MEMORY_SCOPE_AGENT);
          unsigned f2a = __hip_atomic_load(flags2 + lane * FLS, __ATOMIC_RELAXED, __HIP_MEMORY_SCOPE_AGENT);
          unsigned f2b = __hip_atomic_load(flags2 + (64 + (lane & 31)) * FLS, __ATOMIC_RELAXED, __HIP_MEMORY_SCOPE_AGENT);
          if (__all(f1a >= need1) && __all(f1b >= need1) &&
              __all(f2a >= need2) && __all(f2b >= need2)) break;
        }
      } else if (t > 0) {
        const unsigned need = (unsigned)t;
        for (;;) {
          unsigned fa = __hip_atomic_load(flags1 + lane * FLS, __ATOMIC_RELAXED, __HIP_MEMORY_SCOPE_AGENT);
          unsigned fb = __hip_atomic_load(flags1 + (64 + (lane & 31)) * FLS, __ATOMIC_RELAXED, __HIP_MEMORY_SCOPE_AGENT);
          if (__all(fa >= need) && __all(fb >= need)) break;
        }
      }
    }
    __syncthreads();                 // A: data for step t is globally visible
    asm volatile("" ::: "memory");

    f32x4 a0 = {0.f, 0.f, 0.f, 0.f}, a1 = {0.f, 0.f, 0.f, 0.f};
    if (layer) {
      const unsigned short* ap = hseq1 + ((size_t)t * Bb + brow) * Hh + kq * 8;
      bf16x8 areg[24];
      #pragma unroll
      for (int kk = 0; kk < 24; ++kk) areg[kk] = *(const bf16x8*)(ap + kk * 32);
      #pragma unroll
      for (int kk = 0; kk < 24; ++kk) {
        bf16x8 bfr = *(const bf16x8*)&Wih[c * Hh + (((kk * 4 + kq) ^ (c & 7)) * 8)];
        if (kk & 1) a1 = __builtin_amdgcn_mfma_f32_16x16x32_bf16(areg[kk], bfr, a1, 0, 0, 0);
        else        a0 = __builtin_amdgcn_mfma_f32_16x16x32_bf16(areg[kk], bfr, a0, 0, 0, 0);
      }
    }
    if (t > 0) {
      const unsigned short* ap = hout + ((size_t)(t - 1) * Bb + brow) * Hh + kq * 8;
      bf16x8 areg[24];
      #pragma unroll
      for (int kk = 0; kk < 24; ++kk) areg[kk] = *(const bf16x8*)(ap + kk * 32);
      #pragma unroll
      for (int kk = 0; kk < 24; ++kk) {
        bf16x8 bfr = *(const bf16x8*)&Whh[c * Hh + (((kk * 4 + kq) ^ (c & 7)) * 8)];
        if (kk & 1) a1 = __builtin_amdgcn_mfma_f32_16x16x32_bf16(areg[kk], bfr, a1, 0, 0, 0);
        else        a0 = __builtin_amdgcn_mfma_f32_16x16x32_bf16(areg[kk], bfr, a0, 0, 0, 0);
      }
    }

    // activations -> gsm
    #pragma unroll
    for (int r = 0; r < 4; ++r) {
      float v = a0[r] + a1[r] + (layer ? bl : bf2f(gc[r]));
      float s = 1.f / (1.f + __expf(-kmul * v));
      gsm[mtile * 16 + kq * 4 + r][c] = amul * s + aadd;
    }
    // non-publisher waves prefetch next pre-gates now (off the publish path)
    if (!layer && w != 0 && t + 1 < Ss) {
      #pragma unroll
      for (int r = 0; r < 4; ++r) {
        int b = mtile * 16 + kq * 4 + r;
        gc[r] = g_bf[((size_t)(t + 1) * Bb + b) * G4 + gcol];
      }
    }
    __syncthreads();                 // B: gsm complete

    if (w == 0) {
      // pointwise c/h: 64 lanes x (1 batch, 4 units); publish; flag
      const int b = lane & 31, u4 = (lane >> 5) * 4;
      float hv[4];
      #pragma unroll
      for (int j = 0; j < 4; ++j) {
        const int u = u4 + j;
        float iv = gsm[b][u], fv = gsm[b][8 + u], gv = gsm[b][16 + u], ov = gsm[b][24 + u];
        float cn = fv * cc[j] + iv * gv;
        cc[j] = cn;
        float e = __expf(-2.f * cn);
        hv[j] = ov * (1.f - e) / (1.f + e);
      }
      uint32_t pk0 = (uint32_t)f2bf(hv[0]) | ((uint32_t)f2bf(hv[1]) << 16);
      uint32_t pk1 = (uint32_t)f2bf(hv[2]) | ((uint32_t)f2bf(hv[3]) << 16);
      uint32_t* hp = (uint32_t*)(hout + ((size_t)t * Bb + b) * Hh + u0 + u4);
      __hip_atomic_store(hp + 0, pk0, __ATOMIC_RELAXED, __HIP_MEMORY_SCOPE_AGENT);
      __hip_atomic_store(hp + 1, pk1, __ATOMIC_RELAXED, __HIP_MEMORY_SCOPE_AGENT);
      asm volatile("s_waitcnt vmcnt(0)" ::: "memory");   // h acked at LLC
      if (lane == 0)
        __hip_atomic_store(myflag, (unsigned)(t + 1), __ATOMIC_RELAXED, __HIP_MEMORY_SCOPE_AGENT);
      if (!layer && t + 1 < Ss) {
        #pragma unroll
        for (int r = 0; r < 4; ++r) {
          int b2 = mtile * 16 + kq * 4 + r;
          gc[r] = g_bf[((size_t)(t + 1) * Bb + b2) * G4 + gcol];
        }
      }
    }
  }
}

// ---------------- pool reduce over partials ----------------
__global__ __launch_bounds__(256) void k_pool_reduce(const float* __restrict__ partial,
                                                     const float* __restrict__ pool_b,
                                                     float* __restrict__ seq_out) {
  int i = blockIdx.x * 256 + threadIdx.x;
  float acc = pool_b[i % Hh];
  #pragma unroll 8
  for (int t = 0; t < Ss; ++t) acc += partial[(size_t)t * (Bb * Hh) + i];
  seq_out[i] = acc;
}

// ---------------- entity masked max + logits ----------------
__global__ __launch_bounds__(256) void k_entity_logits(const unsigned short* __restrict__ hseq2,
                                                       const float* __restrict__ seq_out,
                                                       const int* __restrict__ entity_ids,
                                                       const float* __restrict__ lin_w,
                                                       const float* __restrict__ lin_b,
                                                       float* __restrict__ logits_ws,
                                                       float* __restrict__ dlogits) {
  const int b = blockIdx.x, tid = threadIdx.x;
  float m0 = -1e30f, m1 = -1e30f, m2 = -1e30f;
  for (int s = 0; s < Ss; ++s) {
    bool e = entity_ids[b * Ss + s] == 1;
    const unsigned short* row = hseq2 + ((size_t)s * Bb + b) * Hh;
    float v0 = bf2f(row[tid]);
    float v1 = bf2f(row[256 + tid]);
    float v2 = bf2f(row[512 + tid]);
    v0 = e ? v0 : 0.f; v1 = e ? v1 : 0.f; v2 = e ? v2 : 0.f;
    m0 = fmaxf(m0, v0); m1 = fmaxf(m1, v1); m2 = fmaxf(m2, v2);
  }
  __shared__ float red[512];
  float p0 = 0.f, p1 = 0.f;
  float mm[3] = {m0, m1, m2};
  #pragma unroll
  for (int j = 0; j < 3; ++j) {
    int n = j * 256 + tid;
    float bo = fmaxf(mm[j], seq_out[b * Hh + n]);
    p0 += bo * lin_w[n * 2 + 0];
    p1 += bo * lin_w[n * 2 + 1];
  }
  red[tid] = p0; red[256 + tid] = p1;
  __syncthreads();
  for (int off = 128; off > 0; off >>= 1) {
    if (tid < off) { red[tid] += red[tid + off]; red[256 + tid] += red[256 + tid + off]; }
    __syncthreads();
  }
  if (tid == 0) {
    float l0 = red[0] + lin_b[0], l1 = red[256] + lin_b[1];
    logits_ws[b * 2] = l0; logits_ws[b * 2 + 1] = l1;
    dlogits[b * 2] = l0;  dlogits[b * 2 + 1] = l1;
  }
}

// ---------------- BCEWithLogits mean loss ----------------
__global__ void k_loss(const float* __restrict__ logits, const int* __restrict__ lab,
                       float* __restrict__ dout) {
  __shared__ float red[64];
  int i = threadIdx.x;
  float l = logits[i];
  float y = (float)lab[i];
  red[i] = fmaxf(l, 0.f) - l * y + log1pf(__expf(-fabsf(l)));
  __syncthreads();
  for (int off = 32; off > 0; off >>= 1) {
    if (i < off) red[i] += red[i + off];
    __syncthreads();
  }
  if (i == 0) dout[0] = red[0] * (1.f / 64.f);
}

// ---------------- launcher ----------------
extern "C" void kernel_launch(void* const* d_in, const int* in_sizes, int n_in,
                              void* d_out, int out_size, void* d_ws, size_t ws_size,
                              hipStream_t stream) {
  const int*   input_ids  = (const int*)d_in[0];
  const int*   seq_label  = (const int*)d_in[3];
  const int*   entity_ids = (const int*)d_in[4];
  const float* embed      = (const float*)d_in[5];
  const float* w_ih0      = (const float*)d_in[6];
  const float* w_hh0      = (const float*)d_in[7];
  const float* b_ih0      = (const float*)d_in[8];
  const float* b_hh0      = (const float*)d_in[9];
  const float* w_ih1      = (const float*)d_in[10];
  const float* w_hh1      = (const float*)d_in[11];
  const float* b_ih1      = (const float*)d_in[12];
  const float* b_hh1      = (const float*)d_in[13];
  const float* pool_w     = (const float*)d_in[14];
  const float* pool_b     = (const float*)d_in[15];
  const float* lin_w      = (const float*)d_in[16];
  const float* lin_b      = (const float*)d_in[17];
  float* out = (float*)d_out;

  const size_t SZ_XO = (size_t)Bb * Ss * Hh * 2;   // 12.58 MB
  const size_t SZ_W  = (size_t)G4 * Hh * 2;        //  4.72 MB
  const size_t SZ_G  = (size_t)Bb * Ss * G4 * 2;   // 50.33 MB
  char* ws = (char*)d_ws;
  size_t off = 0;
  unsigned short* x_bf   = (unsigned short*)(ws + off); off += SZ_XO;
  unsigned short* wb_ih0 = (unsigned short*)(ws + off); off += SZ_W;
  unsigned short* wb_hh0 = (unsigned short*)(ws + off); off += SZ_W;
  unsigned short* wb_ih1 = (unsigned short*)(ws + off); off += SZ_W;
  unsigned short* wb_hh1 = (unsigned short*)(ws + off); off += SZ_W;
  unsigned short* g_bf   = (unsigned short*)(ws + off); off += SZ_G;
  unsigned short* hseq1  = (unsigned short*)(ws + off); off += SZ_XO;
  unsigned short* hseq2  = (unsigned short*)(ws + off); off += SZ_XO;
  float*          seq_out= (float*)(ws + off);          off += (size_t)Bb * Hh * 4;
  float*          logits = (float*)(ws + off);          off += 1024;
  unsigned int*   syncb  = (unsigned int*)(ws + off);   off += 8192;
  // partial (25.2 MB fp32) aliases x_bf..wb_ih1 (26.7 MB), all dead before the
  // first flags2>=1 can fire (gemm consumed x/wb_ih0; wb_hh0/wb_ih1 staged to
  // LDS before any layer finishes step 0). wb_hh1 (needed at staging) is beyond.
  float*          partial = (float*)ws;

  hipMemsetAsync(syncb, 0, 8192, stream);

  k_embed<<<Bb * Ss, 256, 0, stream>>>(input_ids, embed, x_bf);
  int n4 = (G4 * Hh) / 4;
  int cgrid = (n4 + 255) / 256;
  k_cast<<<cgrid, 256, 0, stream>>>(w_ih0, wb_ih0, n4);
  k_cast<<<cgrid, 256, 0, stream>>>(w_hh0, wb_hh0, n4);
  k_cast<<<cgrid, 256, 0, stream>>>(w_ih1, wb_ih1, n4);
  k_cast<<<cgrid, 256, 0, stream>>>(w_hh1, wb_hh1, n4);

  dim3 ggrid(MR / 128, G4 / 128);
  k_gemm_bt<<<ggrid, 256, 0, stream>>>(x_bf, wb_ih0, g_bf, b_ih0, b_hh0, MR, G4, Hh);

  k_lstm2<<<2 * NWGL + NPOOL, 256, 0, stream>>>(g_bf, wb_hh0, wb_ih1, wb_hh1,
                                                b_ih1, b_hh1, hseq1, hseq2,
                                                pool_w, partial, syncb);

  k_pool_reduce<<<(Bb * Hh) / 256, 256, 0, stream>>>(partial, pool_b, seq_out);
  k_entity_logits<<<Bb, 256, 0, stream>>>(hseq2, seq_out, entity_ids, lin_w, lin_b,
                                          logits, out + 1);
  k_loss<<<1, 64, 0, stream>>>(logits, seq_label, out);
}